// Round 3
// baseline (342.633 us; speedup 1.0000x reference)
//
#include <hip/hip_runtime.h>
#include <stdint.h>

#define TTOK 1024
#define DMODEL 1024
#define NEXP 16
#define TOPK 4
#define INTER 512
#define NSHI 1024
#define RSCALE 2.5f

typedef __bf16 bf16;
typedef __bf16 bf16x8 __attribute__((ext_vector_type(8)));
typedef __bf16 bf16x4 __attribute__((ext_vector_type(4)));
typedef float f32x4 __attribute__((ext_vector_type(4)));

__device__ __forceinline__ void glds16(void* lds, const void* g) {
  __builtin_amdgcn_global_load_lds(
      (const __attribute__((address_space(1))) unsigned int*)g,
      (__attribute__((address_space(3))) unsigned int*)lds, 16, 0, 0);
}

// ---------------- x fp32 -> bf16 ----------------
__global__ __launch_bounds__(256)
void xcvt_kernel(const float* __restrict__ x, bf16* __restrict__ xbf) {
  const int i = blockIdx.x * 256 + threadIdx.x;
  const float4 v = ((const float4*)x)[i];
  bf16x4 o;
  o.x = (bf16)v.x; o.y = (bf16)v.y; o.z = (bf16)v.z; o.w = (bf16)v.w;
  ((bf16x4*)xbf)[i] = o;
}

// ---------------- scores: logits = x @ gw^T, fp32 exact ----------------
__global__ __launch_bounds__(256)
void scores_kernel(const float* __restrict__ x, const float* __restrict__ gw,
                   float* __restrict__ scores) {
  __shared__ float gws[16 * 1024];
  const int tid = threadIdx.x;
  const float4* gw4 = (const float4*)gw;
#pragma unroll
  for (int i0 = 0; i0 < 4096; i0 += 256) {
    const int i = i0 + tid;
    const int e = i >> 8;
    const int dq = (i & 255) << 2;
    const int dd = (dq + 4 * e) & 1023;
    ((float4*)gws)[(e << 8) + (dd >> 2)] = gw4[i];
  }
  __syncthreads();
  const int kq = tid >> 6;
  const int lane = tid & 63;
  const int tl = lane >> 4;
  const int e = lane & 15;
  const long token = (long)blockIdx.x * 4 + tl;
  float acc = 0.f;
  const int dbase = kq * 256;
#pragma unroll 8
  for (int i = 0; i < 256; i += 4) {
    const int d = dbase + i;
    const float4 xv = *(const float4*)&x[token * DMODEL + d];
    const float4 wv = *(const float4*)&gws[(e << 10) + ((d + 4 * e) & 1023)];
    acc += xv.x * wv.x + xv.y * wv.y + xv.z * wv.z + xv.w * wv.w;
  }
  __syncthreads();
  gws[kq * 64 + lane] = acc;
  __syncthreads();
  if (kq == 0) {
    const float s = gws[lane] + gws[64 + lane] + gws[128 + lane] + gws[192 + lane];
    scores[token * 16 + e] = s;
  }
}

// ---------------- top-k: one thread per token ----------------
__global__ __launch_bounds__(256)
void topk_kernel(const float* __restrict__ scores, const float* __restrict__ gb,
                 int* __restrict__ tokIdx, float* __restrict__ tokW,
                 int* __restrict__ counts) {
  __shared__ int h[NEXP];
  const int tid = threadIdx.x;
  if (tid < NEXP) h[tid] = 0;
  __syncthreads();
  const int t = blockIdx.x * 256 + tid;
  float sc[NEXP], s[NEXP];
#pragma unroll
  for (int e = 0; e < NEXP; ++e) {
    const float l = scores[t * NEXP + e];
    sc[e] = 1.f / (1.f + expf(-l));
    s[e] = sc[e] + gb[e];
  }
  float gsc[4];
#pragma unroll
  for (int g = 0; g < 4; ++g) {
    const float a = s[4 * g], b = s[4 * g + 1], c = s[4 * g + 2], d = s[4 * g + 3];
    gsc[g] = fmaxf(fmaxf(fmaxf(a + b, a + c), fmaxf(a + d, b + c)),
                   fmaxf(b + d, c + d));
  }
  int g0 = 0;
  for (int g = 1; g < 4; ++g) if (gsc[g] > gsc[g0]) g0 = g;
  int g1 = (g0 == 0) ? 1 : 0;
  for (int g = 0; g < 4; ++g) if (g != g0 && gsc[g] > gsc[g1]) g1 = g;
  float m[NEXP];
#pragma unroll
  for (int e = 0; e < NEXP; ++e) {
    const int g = e >> 2;
    m[e] = (g == g0 || g == g1) ? s[e] : -1.f;
  }
  int idx[TOPK]; float wv[TOPK]; float wsum = 0.f;
  for (int k = 0; k < TOPK; ++k) {
    int am = 0; float best = m[0];
    for (int e2 = 1; e2 < NEXP; ++e2)
      if (m[e2] > best) { best = m[e2]; am = e2; }
    idx[k] = am; wv[k] = sc[am]; wsum += sc[am]; m[am] = -2.f;
  }
  const float scl = RSCALE / wsum;
  for (int k = 0; k < TOPK; ++k) {
    tokIdx[t * TOPK + k] = idx[k];
    tokW[t * TOPK + k] = wv[k] * scl;
    atomicAdd(&h[idx[k]], 1);
  }
  __syncthreads();
  if (tid < NEXP) atomicAdd(&counts[tid], h[tid]);
}

__global__ void prefix_kernel(const int* __restrict__ counts, int* __restrict__ offs,
                              int* __restrict__ cursors) {
  if (threadIdx.x == 0) {
    int acc = 0;
    for (int e = 0; e < NEXP; ++e) { offs[e] = acc; cursors[e] = acc; acc += counts[e]; }
    offs[NEXP] = acc;
  }
}

__global__ __launch_bounds__(256)
void fill_kernel(const int* __restrict__ tokIdx, const float* __restrict__ tokW,
                 int* __restrict__ cursors, int* __restrict__ slotTok,
                 float* __restrict__ slotW) {
  __shared__ int h[NEXP], base[NEXP];
  const int tid = threadIdx.x;
  if (tid < NEXP) h[tid] = 0;
  __syncthreads();
  const int t = blockIdx.x * 256 + tid;
  int myE[TOPK], myR[TOPK];
#pragma unroll
  for (int k = 0; k < TOPK; ++k) {
    myE[k] = tokIdx[t * TOPK + k];
    myR[k] = atomicAdd(&h[myE[k]], 1);
  }
  __syncthreads();
  if (tid < NEXP) base[tid] = atomicAdd(&cursors[tid], h[tid]);
  __syncthreads();
#pragma unroll
  for (int k = 0; k < TOPK; ++k) {
    const int slot = base[myE[k]] + myR[k];
    slotTok[slot] = t;
    slotW[slot] = tokW[t * TOPK + k];
  }
}

// ---------------- gate+up grouped GEMM: fp32 B in-register convert, LDS dbuf ----------------
// z = 0..15 routed (rows = compact slots), z = 16 shared (rows = tokens). K = 1024.
__global__ __launch_bounds__(256)
void gateup_gemm(const bf16* __restrict__ xbf, const int* __restrict__ slotTok,
                 const int* __restrict__ offs, const float* __restrict__ Wg,
                 const float* __restrict__ Wu, const float* __restrict__ Sg,
                 const float* __restrict__ Su, bf16* __restrict__ outR,
                 bf16* __restrict__ outS) {
  const int z = blockIdx.z;
  const bool shd = (z == NEXP);
  const int nTiles = shd ? NSHI / 128 : INTER / 128;
  if ((int)blockIdx.x >= nTiles) return;
  const int rowStart = (shd ? 0 : offs[z]) + blockIdx.y * 128;
  const int rowEnd = shd ? TTOK : offs[z + 1];
  if (rowStart >= rowEnd) return;
  const int n0 = blockIdx.x * 128;
  const float* wg = shd ? Sg : Wg + (long)z * (INTER * DMODEL);
  const float* wu = shd ? Su : Wu + (long)z * (INTER * DMODEL);
  bf16* outI = shd ? outS : outR;
  const int ldI = shd ? NSHI : INTER;

  __shared__ __attribute__((aligned(16))) bf16 As[2][4][128][8];
  __shared__ __attribute__((aligned(16))) bf16 Bg[2][4][128][8];
  __shared__ __attribute__((aligned(16))) bf16 Bu[2][4][128][8];
  __shared__ int tokS[128];

  const int tid = threadIdx.x;
  const int lane = tid & 63;
  const int wv = tid >> 6;
  if (tid < 128) {
    const int r = rowStart + tid;
    tokS[tid] = shd ? (r < rowEnd ? r : rowStart)
                    : slotTok[r < rowEnd ? r : rowStart];
  }
  __syncthreads();

  const int kc = wv;  // A: wave wv stages k-octet kc
  const long t0 = tokS[lane];
  const long t1 = tokS[64 + lane];
  const bf16* a0 = xbf + t0 * DMODEL + kc * 8;
  const bf16* a1 = xbf + t1 * DMODEL + kc * 8;

  // B staging map: 8 threads/row, 4 row-passes
  const int brow = tid >> 3;
  const int bfq = tid & 7;
  const float* gsrc = wg + (long)(n0 + brow) * DMODEL + bfq * 4;
  const float* usrc = wu + (long)(n0 + brow) * DMODEL + bfq * 4;
  const int bkq = bfq >> 1;
  const int boff = (bfq & 1) * 4;

  const int q = lane >> 4;
  const int l15 = lane & 15;
  const int wm = (wv >> 1) * 64;
  const int wn = (wv & 1) * 64;

  float4 gReg[4], uReg[4];

#define LOADB(K0)                                                      \
  {                                                                    \
    _Pragma("unroll") for (int p = 0; p < 4; ++p) {                    \
      gReg[p] = *(const float4*)(gsrc + (long)p * 32 * DMODEL + (K0)); \
      uReg[p] = *(const float4*)(usrc + (long)p * 32 * DMODEL + (K0)); \
    }                                                                  \
  }
#define WRITEB(BUF)                                                    \
  {                                                                    \
    _Pragma("unroll") for (int p = 0; p < 4; ++p) {                    \
      bf16x4 g, u;                                                     \
      g.x = (bf16)gReg[p].x; g.y = (bf16)gReg[p].y;                    \
      g.z = (bf16)gReg[p].z; g.w = (bf16)gReg[p].w;                    \
      u.x = (bf16)uReg[p].x; u.y = (bf16)uReg[p].y;                    \
      u.z = (bf16)uReg[p].z; u.w = (bf16)uReg[p].w;                    \
      *(bf16x4*)&Bg[BUF][bkq][p * 32 + brow][boff] = g;                \
      *(bf16x4*)&Bu[BUF][bkq][p * 32 + brow][boff] = u;                \
    }                                                                  \
  }
#define ISSUEA(BUF, K0)                        \
  {                                            \
    glds16(&As[BUF][kc][0][0], a0 + (K0));     \
    glds16(&As[BUF][kc][64][0], a1 + (K0));    \
  }

  const f32x4 fz = {0.f, 0.f, 0.f, 0.f};
  f32x4 accG[4][4], accU[4][4];
#pragma unroll
  for (int i = 0; i < 4; ++i)
#pragma unroll
    for (int j = 0; j < 4; ++j) { accG[i][j] = fz; accU[i][j] = fz; }

  // prologue: stage 0, prefetch regs for stage 1
  LOADB(0);
  ISSUEA(0, 0);
  WRITEB(0);
  LOADB(32);
  __syncthreads();

  int buf = 0;
  for (int k0 = 0; k0 < DMODEL; k0 += 32) {
    const int nxt = buf ^ 1;
    if (k0 + 32 < DMODEL) {
      ISSUEA(nxt, k0 + 32);
      WRITEB(nxt);                       // regs hold k0+32 data
      if (k0 + 64 < DMODEL) LOADB(k0 + 64);
    }
    bf16x8 aF[4], gF[4], uF[4];
#pragma unroll
    for (int mi = 0; mi < 4; ++mi)
      aF[mi] = *(const bf16x8*)&As[buf][q][wm + mi * 16 + l15][0];
#pragma unroll
    for (int ni = 0; ni < 4; ++ni) {
      gF[ni] = *(const bf16x8*)&Bg[buf][q][wn + ni * 16 + l15][0];
      uF[ni] = *(const bf16x8*)&Bu[buf][q][wn + ni * 16 + l15][0];
    }
#pragma unroll
    for (int mi = 0; mi < 4; ++mi)
#pragma unroll
      for (int ni = 0; ni < 4; ++ni) {
        accG[mi][ni] = __builtin_amdgcn_mfma_f32_16x16x32_bf16(aF[mi], gF[ni], accG[mi][ni], 0, 0, 0);
        accU[mi][ni] = __builtin_amdgcn_mfma_f32_16x16x32_bf16(aF[mi], uF[ni], accU[mi][ni], 0, 0, 0);
      }
    __syncthreads();
    buf = nxt;
  }
#undef LOADB
#undef WRITEB
#undef ISSUEA

#pragma unroll
  for (int mi = 0; mi < 4; ++mi)
#pragma unroll
    for (int r = 0; r < 4; ++r) {
      const int rowLoc = wm + mi * 16 + q * 4 + r;
      const int slotRow = rowStart + rowLoc;
      if (slotRow < rowEnd) {
#pragma unroll
        for (int ni = 0; ni < 4; ++ni) {
          const float gg = accG[mi][ni][r];
          const float uu = accU[mi][ni][r];
          const float sv = gg / (1.f + __expf(-gg)) * uu;
          outI[(long)slotRow * ldI + (n0 + wn + ni * 16 + l15)] = (bf16)sv;
        }
      }
    }
}

// ---------------- down grouped GEMM: split-K x2, fp32 B convert, dbuf, atomic scatter ----------------
// blockIdx.z = z2*2 + ks;  z2 = 0..15 routed (K=512), z2 = 16 shared (K=1024).
__global__ __launch_bounds__(256, 2)
void down_gemm(const bf16* __restrict__ AR, const bf16* __restrict__ AS,
               const int* __restrict__ slotTok, const float* __restrict__ slotW,
               const int* __restrict__ offs, const float* __restrict__ Wd,
               const float* __restrict__ Sd, float* __restrict__ out) {
  const int z = blockIdx.z >> 1;
  const int ks = blockIdx.z & 1;
  const bool shd = (z == NEXP);
  const int rowStart = (shd ? 0 : offs[z]) + blockIdx.y * 128;
  const int rowEnd = shd ? TTOK : offs[z + 1];
  if (rowStart >= rowEnd) return;
  const int n0 = blockIdx.x * 128;
  const int KdF = shd ? NSHI : INTER;     // full K
  const int Kh = KdF >> 1;                // this block's K extent
  const int kb = ks * Kh;                 // k base
  const bf16* A = shd ? AS : AR;
  const float* wd = shd ? Sd : Wd + (long)z * (DMODEL * INTER);

  __shared__ __attribute__((aligned(16))) bf16 As[2][4][128][8];
  __shared__ __attribute__((aligned(16))) bf16 Bs[2][4][128][8];
  __shared__ int tokS[128];
  __shared__ float wS[128];

  const int tid = threadIdx.x;
  const int lane = tid & 63;
  const int wv = tid >> 6;
  if (tid < 128) {
    const int r = rowStart + tid;
    const bool valid = r < rowEnd;
    tokS[tid] = shd ? r : (valid ? slotTok[r] : 0);
    wS[tid] = shd ? 1.f : (valid ? slotW[r] : 0.f);
  }
  __syncthreads();

  const int kc = wv;
  const bf16* a0 = A + (long)(rowStart + lane) * KdF + kb + kc * 8;
  const bf16* a1 = a0 + (long)64 * KdF;

  const int brow = tid >> 3;
  const int bfq = tid & 7;
  const float* bsrc = wd + (long)(n0 + brow) * KdF + kb + bfq * 4;
  const int bkq = bfq >> 1;
  const int boff = (bfq & 1) * 4;

  const int q = lane >> 4;
  const int l15 = lane & 15;
  const int wm = (wv >> 1) * 64;
  const int wn = (wv & 1) * 64;

  float4 bReg[4];

#define LOADB(K0)                                                      \
  {                                                                    \
    _Pragma("unroll") for (int p = 0; p < 4; ++p)                      \
        bReg[p] = *(const float4*)(bsrc + (long)p * 32 * KdF + (K0));  \
  }
#define WRITEB(BUF)                                                    \
  {                                                                    \
    _Pragma("unroll") for (int p = 0; p < 4; ++p) {                    \
      bf16x4 b;                                                        \
      b.x = (bf16)bReg[p].x; b.y = (bf16)bReg[p].y;                    \
      b.z = (bf16)bReg[p].z; b.w = (bf16)bReg[p].w;                    \
      *(bf16x4*)&Bs[BUF][bkq][p * 32 + brow][boff] = b;                \
    }                                                                  \
  }
#define ISSUEA(BUF, K0)                        \
  {                                            \
    glds16(&As[BUF][kc][0][0], a0 + (K0));     \
    glds16(&As[BUF][kc][64][0], a1 + (K0));    \
  }

  const f32x4 fz = {0.f, 0.f, 0.f, 0.f};
  f32x4 acc[4][4];
#pragma unroll
  for (int i = 0; i < 4; ++i)
#pragma unroll
    for (int j = 0; j < 4; ++j) acc[i][j] = fz;

  LOADB(0);
  ISSUEA(0, 0);
  WRITEB(0);
  LOADB(32);
  __syncthreads();

  int buf = 0;
  for (int k0 = 0; k0 < Kh; k0 += 32) {
    const int nxt = buf ^ 1;
    if (k0 + 32 < Kh) {
      ISSUEA(nxt, k0 + 32);
      WRITEB(nxt);
      if (k0 + 64 < Kh) LOADB(k0 + 64);
    }
    bf16x8 aF[4], bF[4];
#pragma unroll
    for (int mi = 0; mi < 4; ++mi)
      aF[mi] = *(const bf16x8*)&As[buf][q][wm + mi * 16 + l15][0];
#pragma unroll
    for (int ni = 0; ni < 4; ++ni)
      bF[ni] = *(const bf16x8*)&Bs[buf][q][wn + ni * 16 + l15][0];
#pragma unroll
    for (int mi = 0; mi < 4; ++mi)
#pragma unroll
      for (int ni = 0; ni < 4; ++ni)
        acc[mi][ni] = __builtin_amdgcn_mfma_f32_16x16x32_bf16(aF[mi], bF[ni], acc[mi][ni], 0, 0, 0);
    __syncthreads();
    buf = nxt;
  }
#undef LOADB
#undef WRITEB
#undef ISSUEA

#pragma unroll
  for (int mi = 0; mi < 4; ++mi)
#pragma unroll
    for (int r = 0; r < 4; ++r) {
      const int rowLoc = wm + mi * 16 + q * 4 + r;
      const int slotRow = rowStart + rowLoc;
      if (slotRow < rowEnd) {
        const long tok = tokS[rowLoc];
        const float wgt = wS[rowLoc];
#pragma unroll
        for (int ni = 0; ni < 4; ++ni) {
          const int col = n0 + wn + ni * 16 + l15;
          atomicAdd(&out[tok * DMODEL + col], wgt * acc[mi][ni][r]);
        }
      }
    }
}

extern "C" void kernel_launch(void* const* d_in, const int* in_sizes, int n_in,
                              void* d_out, int out_size, void* d_ws, size_t ws_size,
                              hipStream_t stream) {
  const float* x  = (const float*)d_in[0];
  const float* gw = (const float*)d_in[2];
  const float* gb = (const float*)d_in[3];
  const float* gp = (const float*)d_in[4];
  const float* up = (const float*)d_in[5];
  const float* dp = (const float*)d_in[6];
  const float* sg = (const float*)d_in[7];
  const float* su = (const float*)d_in[8];
  const float* sd = (const float*)d_in[9];
  float* out = (float*)d_out;

  char* base = (char*)d_ws;
  size_t off = 0;
  auto alloc = [&](size_t bytes) -> char* {
    off = (off + 255) & ~(size_t)255;
    char* p = base + off;
    off += bytes;
    return p;
  };
  bf16* xbf = (bf16*)alloc((size_t)TTOK * DMODEL * 2);
  bf16* interRt = (bf16*)alloc((size_t)(TTOK * TOPK + 128) * INTER * 2);
  bf16* interSh = (bf16*)alloc((size_t)TTOK * NSHI * 2);
  float* scores = (float*)alloc((size_t)TTOK * NEXP * 4);
  int* tokIdx = (int*)alloc(TTOK * TOPK * 4);
  float* tokW = (float*)alloc(TTOK * TOPK * 4);
  int* slotTok = (int*)alloc(TTOK * TOPK * 4);
  float* slotW = (float*)alloc(TTOK * TOPK * 4);
  int* counts = (int*)alloc(NEXP * 4);
  int* offs = (int*)alloc((NEXP + 1) * 4);
  int* cursors = (int*)alloc(NEXP * 4);

  hipMemsetAsync(counts, 0, NEXP * 4, stream);
  hipMemsetAsync(out, 0, (size_t)TTOK * DMODEL * 4, stream);

  xcvt_kernel<<<TTOK * DMODEL / 4 / 256, 256, 0, stream>>>(x, xbf);
  scores_kernel<<<TTOK / 4, 256, 0, stream>>>(x, gw, scores);
  topk_kernel<<<TTOK / 256, 256, 0, stream>>>(scores, gb, tokIdx, tokW, counts);
  prefix_kernel<<<1, 64, 0, stream>>>(counts, offs, cursors);
  fill_kernel<<<TTOK / 256, 256, 0, stream>>>(tokIdx, tokW, cursors, slotTok, slotW);

  gateup_gemm<<<dim3(NSHI / 128, TTOK / 128, NEXP + 1), 256, 0, stream>>>(
      xbf, slotTok, offs, gp, up, sg, su, interRt, interSh);
  down_gemm<<<dim3(DMODEL / 128, TTOK / 128, 2 * (NEXP + 1)), 256, 0, stream>>>(
      interRt, interSh, slotTok, slotW, offs, dp, sd, out);
}

// Round 4
// 220.903 us; speedup vs baseline: 1.5511x; 1.5511x over previous
//
#include <hip/hip_runtime.h>
#include <stdint.h>

#define TTOK 1024
#define DMODEL 1024
#define NEXP 16
#define TOPK 4
#define INTER 512
#define NSHI 1024
#define RSCALE 2.5f

typedef __bf16 bf16;
typedef __bf16 bf16x8 __attribute__((ext_vector_type(8)));
typedef __bf16 bf16x4 __attribute__((ext_vector_type(4)));
typedef float f32x4 __attribute__((ext_vector_type(4)));

// LDS oct-plane strides, padded +16B so write banks spread (bank = f(oct,row))
#define APLANE 2064  // 128 rows * 16B + 16
#define BPLANE 1040  // 64 rows * 16B + 16

// ---------------- scores (+ fused x->bf16): logits = x @ gw^T, fp32 exact ----------------
__global__ __launch_bounds__(256)
void scores_kernel(const float* __restrict__ x, const float* __restrict__ gw,
                   float* __restrict__ scores, bf16* __restrict__ xbf) {
  __shared__ float gws[16 * 1024];
  const int tid = threadIdx.x;
  const float4* gw4 = (const float4*)gw;
#pragma unroll
  for (int i0 = 0; i0 < 4096; i0 += 256) {
    const int i = i0 + tid;
    const int e = i >> 8;
    const int dq = (i & 255) << 2;
    const int dd = (dq + 4 * e) & 1023;
    ((float4*)gws)[(e << 8) + (dd >> 2)] = gw4[i];
  }
  // fused x -> bf16 (4 tokens/block, 1024 float4)
  {
    const long xb = (long)blockIdx.x * 1024;
#pragma unroll
    for (int p = 0; p < 4; ++p) {
      const long j = xb + p * 256 + tid;
      const float4 v = ((const float4*)x)[j];
      bf16x4 o;
      o.x = (bf16)v.x; o.y = (bf16)v.y; o.z = (bf16)v.z; o.w = (bf16)v.w;
      ((bf16x4*)xbf)[j] = o;
    }
  }
  __syncthreads();
  const int kq = tid >> 6;
  const int lane = tid & 63;
  const int tl = lane >> 4;
  const int e = lane & 15;
  const long token = (long)blockIdx.x * 4 + tl;
  float acc = 0.f;
  const int dbase = kq * 256;
#pragma unroll 8
  for (int i = 0; i < 256; i += 4) {
    const int d = dbase + i;
    const float4 xv = *(const float4*)&x[token * DMODEL + d];
    const float4 wv = *(const float4*)&gws[(e << 10) + ((d + 4 * e) & 1023)];
    acc += xv.x * wv.x + xv.y * wv.y + xv.z * wv.z + xv.w * wv.w;
  }
  __syncthreads();
  gws[kq * 64 + lane] = acc;
  __syncthreads();
  if (kq == 0) {
    const float s = gws[lane] + gws[64 + lane] + gws[128 + lane] + gws[192 + lane];
    scores[token * 16 + e] = s;
  }
}

// ---------------- top-k: one thread per token ----------------
__global__ __launch_bounds__(256)
void topk_kernel(const float* __restrict__ scores, const float* __restrict__ gb,
                 int* __restrict__ tokIdx, float* __restrict__ tokW,
                 int* __restrict__ counts) {
  __shared__ int h[NEXP];
  const int tid = threadIdx.x;
  if (tid < NEXP) h[tid] = 0;
  __syncthreads();
  const int t = blockIdx.x * 256 + tid;
  float sc[NEXP], s[NEXP];
#pragma unroll
  for (int e = 0; e < NEXP; ++e) {
    const float l = scores[t * NEXP + e];
    sc[e] = 1.f / (1.f + expf(-l));
    s[e] = sc[e] + gb[e];
  }
  float gsc[4];
#pragma unroll
  for (int g = 0; g < 4; ++g) {
    const float a = s[4 * g], b = s[4 * g + 1], c = s[4 * g + 2], d = s[4 * g + 3];
    gsc[g] = fmaxf(fmaxf(fmaxf(a + b, a + c), fmaxf(a + d, b + c)),
                   fmaxf(b + d, c + d));
  }
  int g0 = 0;
  for (int g = 1; g < 4; ++g) if (gsc[g] > gsc[g0]) g0 = g;
  int g1 = (g0 == 0) ? 1 : 0;
  for (int g = 0; g < 4; ++g) if (g != g0 && gsc[g] > gsc[g1]) g1 = g;
  float m[NEXP];
#pragma unroll
  for (int e = 0; e < NEXP; ++e) {
    const int g = e >> 2;
    m[e] = (g == g0 || g == g1) ? s[e] : -1.f;
  }
  int idx[TOPK]; float wv[TOPK]; float wsum = 0.f;
  for (int k = 0; k < TOPK; ++k) {
    int am = 0; float best = m[0];
    for (int e2 = 1; e2 < NEXP; ++e2)
      if (m[e2] > best) { best = m[e2]; am = e2; }
    idx[k] = am; wv[k] = sc[am]; wsum += sc[am]; m[am] = -2.f;
  }
  const float scl = RSCALE / wsum;
  for (int k = 0; k < TOPK; ++k) {
    tokIdx[t * TOPK + k] = idx[k];
    tokW[t * TOPK + k] = wv[k] * scl;
    atomicAdd(&h[idx[k]], 1);
  }
  __syncthreads();
  if (tid < NEXP) atomicAdd(&counts[tid], h[tid]);
}

// ---------------- plan: offsets + flattened tile list ----------------
__global__ void plan_kernel(const int* __restrict__ counts, int* __restrict__ offs,
                            int* __restrict__ cursors, int* __restrict__ tileE,
                            int* __restrict__ tileR, int* __restrict__ tileCnt) {
  if (threadIdx.x == 0) {
    int acc = 0;
    for (int e = 0; e < NEXP; ++e) { offs[e] = acc; cursors[e] = acc; acc += counts[e]; }
    offs[NEXP] = acc;
    int tc = 0;
    for (int e = 0; e < NEXP; ++e)
      for (int r = offs[e]; r < offs[e + 1]; r += 128) { tileE[tc] = e; tileR[tc] = r; ++tc; }
    for (int r = 0; r < TTOK; r += 128) { tileE[tc] = NEXP; tileR[tc] = r; ++tc; }
    tileCnt[0] = tc;  // <= 47 + 8 = 55
  }
}

// ---------------- fill: slot lists + token->slot map ----------------
__global__ __launch_bounds__(256)
void fill_kernel(const int* __restrict__ tokIdx, int* __restrict__ cursors,
                 int* __restrict__ slotTok, int* __restrict__ tokSlot) {
  __shared__ int h[NEXP], base[NEXP];
  const int tid = threadIdx.x;
  if (tid < NEXP) h[tid] = 0;
  __syncthreads();
  const int t = blockIdx.x * 256 + tid;
  int myE[TOPK], myR[TOPK];
#pragma unroll
  for (int k = 0; k < TOPK; ++k) {
    myE[k] = tokIdx[t * TOPK + k];
    myR[k] = atomicAdd(&h[myE[k]], 1);
  }
  __syncthreads();
  if (tid < NEXP) base[tid] = atomicAdd(&cursors[tid], h[tid]);
  __syncthreads();
#pragma unroll
  for (int k = 0; k < TOPK; ++k) {
    const int slot = base[myE[k]] + myR[k];
    slotTok[slot] = t;
    tokSlot[t * TOPK + k] = slot;
  }
}

// ---------------- gate+up grouped GEMM (128M x 64N, BK=64), fused SwiGLU ----------------
__global__ __launch_bounds__(256, 2)
void gateup_gemm(const bf16* __restrict__ xbf, const int* __restrict__ slotTok,
                 const int* __restrict__ offs, const int* __restrict__ tileE,
                 const int* __restrict__ tileR, const int* __restrict__ tileCnt,
                 const float* __restrict__ Wg, const float* __restrict__ Wu,
                 const float* __restrict__ Sg, const float* __restrict__ Su,
                 bf16* __restrict__ interR, bf16* __restrict__ interS) {
  const int y = blockIdx.y;
  if (y >= tileCnt[0]) return;
  const int e = tileE[y];
  const bool shd = (e == NEXP);
  const int n0 = blockIdx.x * 64;
  if (!shd && n0 >= INTER) return;
  const int rowStart = tileR[y];
  const int rowEnd = shd ? rowStart + 128 : offs[e + 1];
  const float* wgp = shd ? Sg : Wg + (long)e * INTER * DMODEL;
  const float* wup = shd ? Su : Wu + (long)e * INTER * DMODEL;

  __shared__ __attribute__((aligned(16))) char As[8 * APLANE];
  __shared__ __attribute__((aligned(16))) char Bg[8 * BPLANE];
  __shared__ __attribute__((aligned(16))) char Bu[8 * BPLANE];
  __shared__ int tokS[128];

  const int tid = threadIdx.x;
  if (tid < 128) {
    const int r = rowStart + tid;
    tokS[tid] = shd ? r : slotTok[r < rowEnd ? r : rowStart];
  }
  __syncthreads();

  // A staging: round p: row = p*32 + (tid>>3), oct = tid&7 -> per-instr 8 rows x 128B
  const int arw = tid >> 3;
  const int aoct = tid & 7;
  const bf16* aSrc[4];
#pragma unroll
  for (int p = 0; p < 4; ++p)
    aSrc[p] = xbf + (long)tokS[p * 32 + arw] * DMODEL + aoct * 8;

  // B staging: 128 threads per matrix; round p: row = p*8 + (u>>4), f4 = u&15
  const int bu_ = tid >> 7;
  const int u = tid & 127;
  const int brw = u >> 4;
  const int bf4 = u & 15;
  const int boct = bf4 >> 1;
  const int bhalf = bf4 & 1;
  const float* bSrc = (bu_ ? wup : wgp) + (long)n0 * DMODEL + bf4 * 4;
  char* bDst = bu_ ? Bu : Bg;

  const int lane = tid & 63;
  const int wv = tid >> 6;
  const int q = lane >> 4;
  const int l15 = lane & 15;
  const int wm = (wv >> 1) * 64;
  const int wn = (wv & 1) * 32;

  const f32x4 fz = {0.f, 0.f, 0.f, 0.f};
  f32x4 accG[4][2], accU[4][2];
#pragma unroll
  for (int i = 0; i < 4; ++i)
#pragma unroll
    for (int j = 0; j < 2; ++j) { accG[i][j] = fz; accU[i][j] = fz; }

  bf16x8 av[4];
  float4 bv[8];
  // prologue loads (k0 = 0)
#pragma unroll
  for (int p = 0; p < 4; ++p) av[p] = *(const bf16x8*)(aSrc[p]);
#pragma unroll
  for (int p = 0; p < 8; ++p)
    bv[p] = *(const float4*)(bSrc + (long)(p * 8 + brw) * DMODEL);

  for (int k0 = 0; k0 < DMODEL; k0 += 64) {
    __syncthreads();  // previous frag reads done
#pragma unroll
    for (int p = 0; p < 4; ++p)
      *(bf16x8*)(As + aoct * APLANE + (p * 32 + arw) * 16) = av[p];
#pragma unroll
    for (int p = 0; p < 8; ++p) {
      bf16x4 w;
      w.x = (bf16)bv[p].x; w.y = (bf16)bv[p].y; w.z = (bf16)bv[p].z; w.w = (bf16)bv[p].w;
      *(bf16x4*)(bDst + boct * BPLANE + (p * 8 + brw) * 16 + bhalf * 8) = w;
    }
    // prefetch next chunk (overlaps LDS-write visibility + barrier)
    const int kn = k0 + 64;
    if (kn < DMODEL) {
#pragma unroll
      for (int p = 0; p < 4; ++p) av[p] = *(const bf16x8*)(aSrc[p] + kn);
#pragma unroll
      for (int p = 0; p < 8; ++p)
        bv[p] = *(const float4*)(bSrc + (long)(p * 8 + brw) * DMODEL + kn);
    }
    __syncthreads();
#pragma unroll
    for (int kb = 0; kb < 2; ++kb) {
      bf16x8 aF[4];
#pragma unroll
      for (int mi = 0; mi < 4; ++mi)
        aF[mi] = *(const bf16x8*)(As + (4 * kb + q) * APLANE + (wm + 16 * mi + l15) * 16);
#pragma unroll
      for (int ni = 0; ni < 2; ++ni) {
        const int br = wn + 16 * ni + l15;
        const bf16x8 gF = *(const bf16x8*)(Bg + (4 * kb + q) * BPLANE + br * 16);
        const bf16x8 uF = *(const bf16x8*)(Bu + (4 * kb + q) * BPLANE + br * 16);
#pragma unroll
        for (int mi = 0; mi < 4; ++mi) {
          accG[mi][ni] = __builtin_amdgcn_mfma_f32_16x16x32_bf16(aF[mi], gF, accG[mi][ni], 0, 0, 0);
          accU[mi][ni] = __builtin_amdgcn_mfma_f32_16x16x32_bf16(aF[mi], uF, accU[mi][ni], 0, 0, 0);
        }
      }
    }
  }

  bf16* outI = shd ? interS : interR;
  const int ldI = shd ? NSHI : INTER;
#pragma unroll
  for (int mi = 0; mi < 4; ++mi)
#pragma unroll
    for (int r = 0; r < 4; ++r) {
      const int rowLoc = wm + 16 * mi + q * 4 + r;
      const int row = rowStart + rowLoc;
      if (row < rowEnd) {
#pragma unroll
        for (int ni = 0; ni < 2; ++ni) {
          const float gg = accG[mi][ni][r];
          const float uu = accU[mi][ni][r];
          const float sv = gg / (1.f + __expf(-gg)) * uu;
          outI[(long)row * ldI + (n0 + wn + 16 * ni + l15)] = (bf16)sv;
        }
      }
    }
}

// ---------------- down grouped GEMM (128M x 64N, BK=64) -> per-slot fp32 rows ----------------
__global__ __launch_bounds__(256, 2)
void down_gemm(const bf16* __restrict__ interR, const bf16* __restrict__ interS,
               const int* __restrict__ offs, const int* __restrict__ tileE,
               const int* __restrict__ tileR, const int* __restrict__ tileCnt,
               const float* __restrict__ Wd, const float* __restrict__ Sd,
               float* __restrict__ dsR, float* __restrict__ dsS) {
  const int y = blockIdx.y;
  if (y >= tileCnt[0]) return;
  const int e = tileE[y];
  const bool shd = (e == NEXP);
  const int n0 = blockIdx.x * 64;
  const int rowStart = tileR[y];
  const int rowEnd = shd ? rowStart + 128 : offs[e + 1];
  const int Kd = shd ? NSHI : INTER;
  const bf16* A = shd ? interS : interR;
  const float* wd = shd ? Sd : Wd + (long)e * DMODEL * INTER;

  __shared__ __attribute__((aligned(16))) char As[8 * APLANE];
  __shared__ __attribute__((aligned(16))) char Bs[8 * BPLANE];

  const int tid = threadIdx.x;
  // A staging (rows sequential, no gather)
  const int arw = tid >> 3;
  const int aoct = tid & 7;
  const bf16* aSrc[4];
#pragma unroll
  for (int p = 0; p < 4; ++p)
    aSrc[p] = A + (long)(rowStart + p * 32 + arw) * Kd + aoct * 8;

  // B staging: 256 threads, 64 rows x 256B: round p: row = p*16 + (tid>>4), f4 = tid&15
  const int brw = tid >> 4;
  const int bf4 = tid & 15;
  const int boct = bf4 >> 1;
  const int bhalf = bf4 & 1;
  const float* bSrc = wd + (long)n0 * Kd + bf4 * 4;

  const int lane = tid & 63;
  const int wv = tid >> 6;
  const int q = lane >> 4;
  const int l15 = lane & 15;
  const int wm = (wv >> 1) * 64;
  const int wn = (wv & 1) * 32;

  const f32x4 fz = {0.f, 0.f, 0.f, 0.f};
  f32x4 acc[4][2];
#pragma unroll
  for (int i = 0; i < 4; ++i)
#pragma unroll
    for (int j = 0; j < 2; ++j) acc[i][j] = fz;

  bf16x8 av[4];
  float4 bv[4];
#pragma unroll
  for (int p = 0; p < 4; ++p) av[p] = *(const bf16x8*)(aSrc[p]);
#pragma unroll
  for (int p = 0; p < 4; ++p)
    bv[p] = *(const float4*)(bSrc + (long)(p * 16 + brw) * Kd);

  for (int k0 = 0; k0 < Kd; k0 += 64) {
    __syncthreads();
#pragma unroll
    for (int p = 0; p < 4; ++p)
      *(bf16x8*)(As + aoct * APLANE + (p * 32 + arw) * 16) = av[p];
#pragma unroll
    for (int p = 0; p < 4; ++p) {
      bf16x4 w;
      w.x = (bf16)bv[p].x; w.y = (bf16)bv[p].y; w.z = (bf16)bv[p].z; w.w = (bf16)bv[p].w;
      *(bf16x4*)(Bs + boct * BPLANE + (p * 16 + brw) * 16 + bhalf * 8) = w;
    }
    const int kn = k0 + 64;
    if (kn < Kd) {
#pragma unroll
      for (int p = 0; p < 4; ++p) av[p] = *(const bf16x8*)(aSrc[p] + kn);
#pragma unroll
      for (int p = 0; p < 4; ++p)
        bv[p] = *(const float4*)(bSrc + (long)(p * 16 + brw) * Kd + kn);
    }
    __syncthreads();
#pragma unroll
    for (int kb = 0; kb < 2; ++kb) {
      bf16x8 aF[4];
#pragma unroll
      for (int mi = 0; mi < 4; ++mi)
        aF[mi] = *(const bf16x8*)(As + (4 * kb + q) * APLANE + (wm + 16 * mi + l15) * 16);
#pragma unroll
      for (int ni = 0; ni < 2; ++ni) {
        const bf16x8 bF = *(const bf16x8*)(Bs + (4 * kb + q) * BPLANE + (wn + 16 * ni + l15) * 16);
#pragma unroll
        for (int mi = 0; mi < 4; ++mi)
          acc[mi][ni] = __builtin_amdgcn_mfma_f32_16x16x32_bf16(aF[mi], bF, acc[mi][ni], 0, 0, 0);
      }
    }
  }

  float* dst = shd ? dsS : dsR;
#pragma unroll
  for (int mi = 0; mi < 4; ++mi)
#pragma unroll
    for (int r = 0; r < 4; ++r) {
      const int rowLoc = wm + 16 * mi + q * 4 + r;
      const int row = rowStart + rowLoc;
      if (row < rowEnd) {
#pragma unroll
        for (int ni = 0; ni < 2; ++ni)
          dst[(long)row * DMODEL + (n0 + wn + 16 * ni + l15)] = acc[mi][ni][r];
      }
    }
}

// ---------------- combine: out[t] = shared[t] + sum_k w * routed[slot_k] ----------------
__global__ __launch_bounds__(256)
void combine_kernel(const float* __restrict__ dsR, const float* __restrict__ dsS,
                    const int* __restrict__ tokSlot, const float* __restrict__ tokW,
                    float* __restrict__ out) {
  const int t = blockIdx.x;
  const int j = threadIdx.x;  // float4 column
  float4 v = ((const float4*)(dsS + (long)t * DMODEL))[j];
#pragma unroll
  for (int k = 0; k < TOPK; ++k) {
    const int s = tokSlot[t * TOPK + k];
    const float w = tokW[t * TOPK + k];
    const float4 r = ((const float4*)(dsR + (long)s * DMODEL))[j];
    v.x += w * r.x; v.y += w * r.y; v.z += w * r.z; v.w += w * r.w;
  }
  ((float4*)(out + (long)t * DMODEL))[j] = v;
}

extern "C" void kernel_launch(void* const* d_in, const int* in_sizes, int n_in,
                              void* d_out, int out_size, void* d_ws, size_t ws_size,
                              hipStream_t stream) {
  const float* x  = (const float*)d_in[0];
  const float* gw = (const float*)d_in[2];
  const float* gb = (const float*)d_in[3];
  const float* gp = (const float*)d_in[4];
  const float* up = (const float*)d_in[5];
  const float* dp = (const float*)d_in[6];
  const float* sg = (const float*)d_in[7];
  const float* su = (const float*)d_in[8];
  const float* sd = (const float*)d_in[9];
  float* out = (float*)d_out;

  char* base = (char*)d_ws;
  size_t off = 0;
  auto alloc = [&](size_t bytes) -> char* {
    off = (off + 255) & ~(size_t)255;
    char* p = base + off;
    off += bytes;
    return p;
  };
  bf16* xbf = (bf16*)alloc((size_t)TTOK * DMODEL * 2);
  bf16* interR = (bf16*)alloc((size_t)(TTOK * TOPK + 128) * INTER * 2);
  bf16* interS = (bf16*)alloc((size_t)TTOK * NSHI * 2);
  float* dsR = (float*)alloc((size_t)TTOK * TOPK * DMODEL * 4);
  float* dsS = (float*)alloc((size_t)TTOK * DMODEL * 4);
  float* scores = (float*)alloc((size_t)TTOK * NEXP * 4);
  int* tokIdx = (int*)alloc(TTOK * TOPK * 4);
  float* tokW = (float*)alloc(TTOK * TOPK * 4);
  int* slotTok = (int*)alloc(TTOK * TOPK * 4);
  int* tokSlot = (int*)alloc(TTOK * TOPK * 4);
  int* counts = (int*)alloc(NEXP * 4);
  int* offs = (int*)alloc((NEXP + 1) * 4);
  int* cursors = (int*)alloc(NEXP * 4);
  int* tileE = (int*)alloc(72 * 4);
  int* tileR = (int*)alloc(72 * 4);
  int* tileCnt = (int*)alloc(4);

  hipMemsetAsync(counts, 0, NEXP * 4, stream);

  scores_kernel<<<TTOK / 4, 256, 0, stream>>>(x, gw, scores, xbf);
  topk_kernel<<<TTOK / 256, 256, 0, stream>>>(scores, gb, tokIdx, tokW, counts);
  plan_kernel<<<1, 64, 0, stream>>>(counts, offs, cursors, tileE, tileR, tileCnt);
  fill_kernel<<<TTOK / 256, 256, 0, stream>>>(tokIdx, cursors, slotTok, tokSlot);

  gateup_gemm<<<dim3(16, 56, 1), 256, 0, stream>>>(
      xbf, slotTok, offs, tileE, tileR, tileCnt, gp, up, sg, su, interR, interS);
  down_gemm<<<dim3(16, 56, 1), 256, 0, stream>>>(
      interR, interS, offs, tileE, tileR, tileCnt, dp, sd, dsR, dsS);
  combine_kernel<<<TTOK, 256, 0, stream>>>(dsR, dsS, tokSlot, tokW, out);
}